// Round 2
// baseline (494.480 us; speedup 1.0000x reference)
//
#include <hip/hip_runtime.h>

#define FDIM 64

// ---------------- CSR-free fallback (round-1 kernel) ----------------
__global__ void dmpnn_scatter_add(const float* __restrict__ edges,
                                  const int* __restrict__ recv,
                                  float* __restrict__ pooled,
                                  long long total) {
    long long tid = (long long)blockIdx.x * blockDim.x + threadIdx.x;
    if (tid >= total) return;
    int e = (int)(tid >> 6);
    int f = (int)(tid & 63);
    float v = edges[tid];
    int node = recv[e];
    atomicAdd(&pooled[(long long)node * FDIM + f], v);
}

// ---------------- Counting-sort pipeline ----------------
__global__ void dmpnn_hist(const int* __restrict__ recv, int* __restrict__ counts, int M) {
    int e = blockIdx.x * blockDim.x + threadIdx.x;
    if (e >= M) return;
    atomicAdd(&counts[recv[e]], 1);
}

// Single-block exclusive scan over N counts -> offsets[0..N], cursor = copy.
__global__ void dmpnn_scan(const int* __restrict__ counts,
                           int* __restrict__ offsets,
                           int* __restrict__ cursor, int N) {
    __shared__ int part[1024];
    int t = threadIdx.x;
    int chunk = (N + 1023) >> 10;
    int lo = t * chunk;
    int hi = lo + chunk; if (hi > N) hi = N; if (lo > N) lo = N;
    int s = 0;
    for (int i = lo; i < hi; ++i) s += counts[i];
    part[t] = s;
    __syncthreads();
    // Hillis-Steele inclusive scan
    for (int d = 1; d < 1024; d <<= 1) {
        int v = (t >= d) ? part[t - d] : 0;
        __syncthreads();
        part[t] += v;
        __syncthreads();
    }
    int base = (t == 0) ? 0 : part[t - 1];
    for (int i = lo; i < hi; ++i) {
        offsets[i] = base;
        cursor[i]  = base;
        base += counts[i];
    }
    if (t == 1023) offsets[N] = part[1023];
}

__global__ void dmpnn_fill(const int* __restrict__ recv,
                           int* __restrict__ cursor,
                           int* __restrict__ perm, int M) {
    int e = blockIdx.x * blockDim.x + threadIdx.x;
    if (e >= M) return;
    int pos = atomicAdd(&cursor[recv[e]], 1);
    perm[pos] = e;
}

// One wave per node: lane = feature, loop over node's edges.
__global__ void dmpnn_aggregate(const float* __restrict__ edges,
                                const int* __restrict__ perm,
                                const int* __restrict__ offsets,
                                float* __restrict__ pooled, int N) {
    int wave = (int)(((long long)blockIdx.x * blockDim.x + threadIdx.x) >> 6);
    int lane = threadIdx.x & 63;
    if (wave >= N) return;
    int lo = offsets[wave];
    int hi = offsets[wave + 1];
    float acc = 0.0f;
    for (int j = lo; j < hi; ++j) {
        int e = perm[j];  // wave-uniform -> broadcast
        acc += edges[(long long)e * FDIM + lane];
    }
    pooled[(long long)wave * FDIM + lane] = acc;
}

// ---------------- Pass 2 (unchanged) ----------------
__global__ void dmpnn_gather_sub(const float* __restrict__ pooled,
                                 const float* __restrict__ edges,
                                 const int* __restrict__ send,
                                 const int* __restrict__ pair,
                                 float* __restrict__ out,
                                 long long total) {
    long long tid = (long long)blockIdx.x * blockDim.x + threadIdx.x;
    if (tid >= total) return;
    int e = (int)(tid >> 4);
    int q = (int)(tid & 15);
    int sn = send[e];
    int pe = pair[e];
    float4 a = *reinterpret_cast<const float4*>(&pooled[(long long)sn * FDIM + q * 4]);
    float4 b = *reinterpret_cast<const float4*>(&edges[(long long)pe * FDIM + q * 4]);
    float4 r;
    r.x = a.x - b.x;
    r.y = a.y - b.y;
    r.z = a.z - b.z;
    r.w = a.w - b.w;
    *reinterpret_cast<float4*>(&out[tid * 4]) = r;
}

extern "C" void kernel_launch(void* const* d_in, const int* in_sizes, int n_in,
                              void* d_out, int out_size, void* d_ws, size_t ws_size,
                              hipStream_t stream) {
    const float* edges      = (const float*)d_in[1];
    const int*   edge_index = (const int*)d_in[2];   // [2, M] flat
    const int*   edge_pairs = (const int*)d_in[3];   // [1, M] flat

    const int N = in_sizes[0] / FDIM;   // 50000
    const int M = in_sizes[1] / FDIM;   // 1000000

    // ws layout: counts[N] | offsets[N+1] | cursor[N] | perm[M] | pooled[N*FDIM]
    size_t need = ((size_t)(3 * N + 1) + (size_t)M) * sizeof(int)
                + (size_t)N * FDIM * sizeof(float);

    const int* recv = edge_index;
    const int* send = edge_index + M;

    if (ws_size >= need) {
        int*   counts  = (int*)d_ws;
        int*   offsets = counts + N;
        int*   cursor  = offsets + (N + 1);
        int*   perm    = cursor + N;
        float* pooled  = (float*)(perm + M);

        hipMemsetAsync(counts, 0, (size_t)N * sizeof(int), stream);

        dmpnn_hist<<<dim3((M + 255) / 256), dim3(256), 0, stream>>>(recv, counts, M);
        dmpnn_scan<<<dim3(1), dim3(1024), 0, stream>>>(counts, offsets, cursor, N);
        dmpnn_fill<<<dim3((M + 255) / 256), dim3(256), 0, stream>>>(recv, cursor, perm, M);

        {
            int wavesPerBlock = 4;                       // 256 threads
            int grid = (N + wavesPerBlock - 1) / wavesPerBlock;
            dmpnn_aggregate<<<dim3(grid), dim3(256), 0, stream>>>(edges, perm, offsets, pooled, N);
        }

        long long total = (long long)M * (FDIM / 4);
        dmpnn_gather_sub<<<dim3((unsigned)((total + 255) / 256)), dim3(256), 0, stream>>>(
            pooled, edges, send, edge_pairs, (float*)d_out, total);
    } else {
        // Fallback: atomic scatter path.
        float* pooled = (float*)d_ws;
        hipMemsetAsync(pooled, 0, (size_t)N * FDIM * sizeof(float), stream);
        long long totalS = (long long)M * FDIM;
        dmpnn_scatter_add<<<dim3((unsigned)((totalS + 255) / 256)), dim3(256), 0, stream>>>(
            edges, recv, pooled, totalS);
        long long total = (long long)M * (FDIM / 4);
        dmpnn_gather_sub<<<dim3((unsigned)((total + 255) / 256)), dim3(256), 0, stream>>>(
            pooled, edges, send, edge_pairs, (float*)d_out, total);
    }
}

// Round 3
// 312.069 us; speedup vs baseline: 1.5845x; 1.5845x over previous
//
#include <hip/hip_runtime.h>

#define FDIM 64
#define BLK 256

// ---------------- Atomic fallback (round-1 kernel) ----------------
__global__ void dmpnn_scatter_add(const float* __restrict__ edges,
                                  const int* __restrict__ recv,
                                  float* __restrict__ pooled,
                                  long long total) {
    long long tid = (long long)blockIdx.x * blockDim.x + threadIdx.x;
    if (tid >= total) return;
    int e = (int)(tid >> 6);
    int f = (int)(tid & 63);
    float v = edges[tid];
    int node = recv[e];
    atomicAdd(&pooled[(long long)node * FDIM + f], v);
}

// ---------------- Counting-sort pipeline ----------------
__global__ void dmpnn_hist(const int* __restrict__ recv, int* __restrict__ counts, int M) {
    int e = blockIdx.x * blockDim.x + threadIdx.x;
    if (e >= M) return;
    atomicAdd(&counts[recv[e]], 1);
}

// scan1: per-block sums of counts
__global__ void dmpnn_scan1(const int* __restrict__ counts, int* __restrict__ blockSums, int N) {
    __shared__ int s[BLK];
    int t = blockIdx.x * BLK + threadIdx.x;
    s[threadIdx.x] = (t < N) ? counts[t] : 0;
    __syncthreads();
    for (int d = BLK >> 1; d > 0; d >>= 1) {
        if (threadIdx.x < (unsigned)d) s[threadIdx.x] += s[threadIdx.x + d];
        __syncthreads();
    }
    if (threadIdx.x == 0) blockSums[blockIdx.x] = s[0];
}

// scan2: exclusive scan of up to 1024 block sums (single block)
__global__ void dmpnn_scan2(const int* __restrict__ blockSums, int* __restrict__ blockBase, int nb) {
    __shared__ int s[1024];
    int t = threadIdx.x;
    s[t] = (t < nb) ? blockSums[t] : 0;
    __syncthreads();
    for (int d = 1; d < 1024; d <<= 1) {
        int v = (t >= d) ? s[t - d] : 0;
        __syncthreads();
        s[t] += v;
        __syncthreads();
    }
    if (t < nb) blockBase[t] = (t == 0) ? 0 : s[t - 1];
}

// scan3: block-local exclusive scan + block base -> offsets, cursor
__global__ void dmpnn_scan3(const int* __restrict__ counts, const int* __restrict__ blockBase,
                            int* __restrict__ offsets, int* __restrict__ cursor, int N) {
    __shared__ int s[BLK];
    int t = blockIdx.x * BLK + threadIdx.x;
    int c = (t < N) ? counts[t] : 0;
    s[threadIdx.x] = c;
    __syncthreads();
    for (int d = 1; d < BLK; d <<= 1) {
        int v = (threadIdx.x >= (unsigned)d) ? s[threadIdx.x - d] : 0;
        __syncthreads();
        s[threadIdx.x] += v;
        __syncthreads();
    }
    int incl = s[threadIdx.x];
    int excl = incl - c;
    int base = blockBase[blockIdx.x];
    if (t < N) {
        offsets[t] = base + excl;
        cursor[t]  = base + excl;
        if (t == N - 1) offsets[N] = base + incl;
    }
}

__global__ void dmpnn_fill(const int* __restrict__ recv,
                           int* __restrict__ cursor,
                           int* __restrict__ perm, int M) {
    int e = blockIdx.x * blockDim.x + threadIdx.x;
    if (e >= M) return;
    int pos = atomicAdd(&cursor[recv[e]], 1);
    perm[pos] = e;
}

// One wave per node: lane = feature. Chunked perm load + shfl broadcast +
// 8-deep unrolled, predicated edge-row loads for latency hiding.
__global__ void dmpnn_aggregate(const float* __restrict__ edges,
                                const int* __restrict__ perm,
                                const int* __restrict__ offsets,
                                float* __restrict__ pooled, int N) {
    int wave = (int)(((long long)blockIdx.x * blockDim.x + threadIdx.x) >> 6);
    int lane = threadIdx.x & 63;
    if (wave >= N) return;
    int lo = offsets[wave];
    int hi = offsets[wave + 1];
    float acc = 0.0f;
    for (int base = lo; base < hi; base += 64) {
        int cnt = hi - base; if (cnt > 64) cnt = 64;
        // one coalesced vector load covers the whole chunk's perm entries
        int e = perm[base + ((lane < cnt) ? lane : (cnt - 1))];
        #pragma unroll 1
        for (int k = 0; k < cnt; k += 8) {
            int e0 = __shfl(e, k + 0, 64);
            int e1 = __shfl(e, k + 1, 64);
            int e2 = __shfl(e, k + 2, 64);
            int e3 = __shfl(e, k + 3, 64);
            int e4 = __shfl(e, k + 4, 64);
            int e5 = __shfl(e, k + 5, 64);
            int e6 = __shfl(e, k + 6, 64);
            int e7 = __shfl(e, k + 7, 64);
            float v0 = edges[(unsigned)((e0 << 6) | lane)];
            float v1 = edges[(unsigned)((e1 << 6) | lane)];
            float v2 = edges[(unsigned)((e2 << 6) | lane)];
            float v3 = edges[(unsigned)((e3 << 6) | lane)];
            float v4 = edges[(unsigned)((e4 << 6) | lane)];
            float v5 = edges[(unsigned)((e5 << 6) | lane)];
            float v6 = edges[(unsigned)((e6 << 6) | lane)];
            float v7 = edges[(unsigned)((e7 << 6) | lane)];
            acc += v0;                                   // k+0 < cnt always
            acc += (k + 1 < cnt) ? v1 : 0.0f;
            acc += (k + 2 < cnt) ? v2 : 0.0f;
            acc += (k + 3 < cnt) ? v3 : 0.0f;
            acc += (k + 4 < cnt) ? v4 : 0.0f;
            acc += (k + 5 < cnt) ? v5 : 0.0f;
            acc += (k + 6 < cnt) ? v6 : 0.0f;
            acc += (k + 7 < cnt) ? v7 : 0.0f;
        }
    }
    pooled[((unsigned)wave << 6) | lane] = acc;
}

// ---------------- Pass 2 (unchanged) ----------------
__global__ void dmpnn_gather_sub(const float* __restrict__ pooled,
                                 const float* __restrict__ edges,
                                 const int* __restrict__ send,
                                 const int* __restrict__ pair,
                                 float* __restrict__ out,
                                 long long total) {
    long long tid = (long long)blockIdx.x * blockDim.x + threadIdx.x;
    if (tid >= total) return;
    int e = (int)(tid >> 4);
    int q = (int)(tid & 15);
    int sn = send[e];
    int pe = pair[e];
    float4 a = *reinterpret_cast<const float4*>(&pooled[(long long)sn * FDIM + q * 4]);
    float4 b = *reinterpret_cast<const float4*>(&edges[(long long)pe * FDIM + q * 4]);
    float4 r;
    r.x = a.x - b.x;
    r.y = a.y - b.y;
    r.z = a.z - b.z;
    r.w = a.w - b.w;
    *reinterpret_cast<float4*>(&out[tid * 4]) = r;
}

extern "C" void kernel_launch(void* const* d_in, const int* in_sizes, int n_in,
                              void* d_out, int out_size, void* d_ws, size_t ws_size,
                              hipStream_t stream) {
    const float* edges      = (const float*)d_in[1];
    const int*   edge_index = (const int*)d_in[2];   // [2, M] flat
    const int*   edge_pairs = (const int*)d_in[3];   // [1, M] flat

    const int N = in_sizes[0] / FDIM;   // 50000
    const int M = in_sizes[1] / FDIM;   // 1000000

    const int* recv = edge_index;
    const int* send = edge_index + M;

    const int NB1 = (N + BLK - 1) / BLK;  // blocks over counts

    // ws layout: counts[N] | offsets[N+1] | cursor[N] | blockSums[NB1] |
    //            blockBase[NB1] | perm[M] | pooled[N*FDIM]
    size_t need = ((size_t)(3 * N + 1) + 2 * (size_t)NB1 + (size_t)M) * sizeof(int)
                + (size_t)N * FDIM * sizeof(float);

    if (ws_size >= need && NB1 <= 1024) {
        int*   counts    = (int*)d_ws;
        int*   offsets   = counts + N;
        int*   cursor    = offsets + (N + 1);
        int*   blockSums = cursor + N;
        int*   blockBase = blockSums + NB1;
        int*   perm      = blockBase + NB1;
        float* pooled    = (float*)(perm + M);

        hipMemsetAsync(counts, 0, (size_t)N * sizeof(int), stream);

        dmpnn_hist<<<dim3((M + BLK - 1) / BLK), dim3(BLK), 0, stream>>>(recv, counts, M);
        dmpnn_scan1<<<dim3(NB1), dim3(BLK), 0, stream>>>(counts, blockSums, N);
        dmpnn_scan2<<<dim3(1), dim3(1024), 0, stream>>>(blockSums, blockBase, NB1);
        dmpnn_scan3<<<dim3(NB1), dim3(BLK), 0, stream>>>(counts, blockBase, offsets, cursor, N);
        dmpnn_fill<<<dim3((M + BLK - 1) / BLK), dim3(BLK), 0, stream>>>(recv, cursor, perm, M);

        {
            int wavesPerBlock = 4;                       // 256 threads
            int grid = (N + wavesPerBlock - 1) / wavesPerBlock;
            dmpnn_aggregate<<<dim3(grid), dim3(BLK), 0, stream>>>(edges, perm, offsets, pooled, N);
        }

        long long total = (long long)M * (FDIM / 4);
        dmpnn_gather_sub<<<dim3((unsigned)((total + BLK - 1) / BLK)), dim3(BLK), 0, stream>>>(
            pooled, edges, send, edge_pairs, (float*)d_out, total);
    } else {
        // Fallback: atomic scatter path.
        float* pooled = (float*)d_ws;
        hipMemsetAsync(pooled, 0, (size_t)N * FDIM * sizeof(float), stream);
        long long totalS = (long long)M * FDIM;
        dmpnn_scatter_add<<<dim3((unsigned)((totalS + BLK - 1) / BLK)), dim3(BLK), 0, stream>>>(
            edges, recv, pooled, totalS);
        long long total = (long long)M * (FDIM / 4);
        dmpnn_gather_sub<<<dim3((unsigned)((total + BLK - 1) / BLK)), dim3(BLK), 0, stream>>>(
            pooled, edges, send, edge_pairs, (float*)d_out, total);
    }
}

// Round 5
// 298.916 us; speedup vs baseline: 1.6542x; 1.0440x over previous
//
#include <hip/hip_runtime.h>

#define FDIM 64
#define BLK 256

typedef float f32x4 __attribute__((ext_vector_type(4)));

// ---------------- Atomic fallback ----------------
__global__ void dmpnn_scatter_add(const float* __restrict__ edges,
                                  const int* __restrict__ recv,
                                  float* __restrict__ pooled,
                                  long long total) {
    long long tid = (long long)blockIdx.x * blockDim.x + threadIdx.x;
    if (tid >= total) return;
    int e = (int)(tid >> 6);
    int f = (int)(tid & 63);
    float v = edges[tid];
    int node = recv[e];
    atomicAdd(&pooled[(long long)node * FDIM + f], v);
}

// ---------------- Counting-sort pipeline ----------------
__global__ void dmpnn_hist(const int* __restrict__ recv, int* __restrict__ counts, int M) {
    int e = blockIdx.x * blockDim.x + threadIdx.x;
    if (e >= M) return;
    atomicAdd(&counts[recv[e]], 1);
}

__global__ void dmpnn_scan1(const int* __restrict__ counts, int* __restrict__ blockSums, int N) {
    __shared__ int s[BLK];
    int t = blockIdx.x * BLK + threadIdx.x;
    s[threadIdx.x] = (t < N) ? counts[t] : 0;
    __syncthreads();
    for (int d = BLK >> 1; d > 0; d >>= 1) {
        if (threadIdx.x < (unsigned)d) s[threadIdx.x] += s[threadIdx.x + d];
        __syncthreads();
    }
    if (threadIdx.x == 0) blockSums[blockIdx.x] = s[0];
}

__global__ void dmpnn_scan2(const int* __restrict__ blockSums, int* __restrict__ blockBase, int nb) {
    __shared__ int s[1024];
    int t = threadIdx.x;
    s[t] = (t < nb) ? blockSums[t] : 0;
    __syncthreads();
    for (int d = 1; d < 1024; d <<= 1) {
        int v = (t >= d) ? s[t - d] : 0;
        __syncthreads();
        s[t] += v;
        __syncthreads();
    }
    if (t < nb) blockBase[t] = (t == 0) ? 0 : s[t - 1];
}

__global__ void dmpnn_scan3(const int* __restrict__ counts, const int* __restrict__ blockBase,
                            int* __restrict__ offsets, int* __restrict__ cursor, int N) {
    __shared__ int s[BLK];
    int t = blockIdx.x * BLK + threadIdx.x;
    int c = (t < N) ? counts[t] : 0;
    s[threadIdx.x] = c;
    __syncthreads();
    for (int d = 1; d < BLK; d <<= 1) {
        int v = (threadIdx.x >= (unsigned)d) ? s[threadIdx.x - d] : 0;
        __syncthreads();
        s[threadIdx.x] += v;
        __syncthreads();
    }
    int incl = s[threadIdx.x];
    int excl = incl - c;
    int base = blockBase[blockIdx.x];
    if (t < N) {
        offsets[t] = base + excl;
        cursor[t]  = base + excl;
        if (t == N - 1) offsets[N] = base + incl;
    }
}

__global__ void dmpnn_fill(const int* __restrict__ recv,
                           int* __restrict__ cursor,
                           int* __restrict__ perm, int M) {
    int e = blockIdx.x * blockDim.x + threadIdx.x;
    if (e >= M) return;
    int pos = atomicAdd(&cursor[recv[e]], 1);
    perm[pos] = e;
}

// One wave per node. lane = (slot s = lane>>4, quad q = lane&15).
// Each load instruction covers 4 edge rows (4 slots x 16 quads x float4 = 1 KB dense).
__global__ void dmpnn_aggregate(const float4* __restrict__ edges4,
                                const int* __restrict__ perm,
                                const int* __restrict__ offsets,
                                float4* __restrict__ pooled4, int N) {
    int wave = (int)(((long long)blockIdx.x * blockDim.x + threadIdx.x) >> 6);
    int lane = threadIdx.x & 63;
    if (wave >= N) return;
    int q = lane & 15;
    int s = lane >> 4;
    int lo = offsets[wave];
    int hi = offsets[wave + 1];
    float4 acc = make_float4(0.f, 0.f, 0.f, 0.f);
    for (int base = lo; base < hi; base += 64) {
        int cnt = hi - base; if (cnt > 64) cnt = 64;
        // coalesced chunk load of perm entries, broadcast later via shfl
        int e = perm[base + ((lane < cnt) ? lane : (cnt - 1))];
        int ng = (cnt + 3) >> 2;
        #pragma unroll 2
        for (int g = 0; g < ng; ++g) {
            int idx = (g << 2) + s;
            int src = (idx < cnt) ? idx : (cnt - 1);
            int ei = __shfl(e, src, 64);
            float4 v = edges4[ei * 16 + q];
            if (idx < cnt) {
                acc.x += v.x; acc.y += v.y; acc.z += v.z; acc.w += v.w;
            }
        }
    }
    // reduce across the 4 slots (lanes differing in bits 4,5)
    acc.x += __shfl_xor(acc.x, 16, 64);
    acc.y += __shfl_xor(acc.y, 16, 64);
    acc.z += __shfl_xor(acc.z, 16, 64);
    acc.w += __shfl_xor(acc.w, 16, 64);
    acc.x += __shfl_xor(acc.x, 32, 64);
    acc.y += __shfl_xor(acc.y, 32, 64);
    acc.z += __shfl_xor(acc.z, 32, 64);
    acc.w += __shfl_xor(acc.w, 32, 64);
    if (s == 0) pooled4[wave * 16 + q] = acc;
}

// ---------------- Pass 2: gather + subtract, NT output stores ----------------
__global__ void dmpnn_gather_sub(const float4* __restrict__ pooled4,
                                 const float4* __restrict__ edges4,
                                 const int* __restrict__ send,
                                 const int* __restrict__ pair,
                                 float4* __restrict__ out4,
                                 long long total) {
    long long tid = (long long)blockIdx.x * blockDim.x + threadIdx.x;
    if (tid >= total) return;
    int e = (int)(tid >> 4);
    int q = (int)(tid & 15);
    int sn = send[e];
    int pe = pair[e];
    float4 a = pooled4[(long long)sn * 16 + q];
    float4 b = edges4[(long long)pe * 16 + q];
    f32x4 r;
    r.x = a.x - b.x;
    r.y = a.y - b.y;
    r.z = a.z - b.z;
    r.w = a.w - b.w;
    __builtin_nontemporal_store(r, (f32x4*)&out4[tid]);
}

extern "C" void kernel_launch(void* const* d_in, const int* in_sizes, int n_in,
                              void* d_out, int out_size, void* d_ws, size_t ws_size,
                              hipStream_t stream) {
    const float* edges      = (const float*)d_in[1];
    const int*   edge_index = (const int*)d_in[2];   // [2, M] flat
    const int*   edge_pairs = (const int*)d_in[3];   // [1, M] flat

    const int N = in_sizes[0] / FDIM;   // 50000
    const int M = in_sizes[1] / FDIM;   // 1000000

    const int* recv = edge_index;
    const int* send = edge_index + M;

    const int NB1 = (N + BLK - 1) / BLK;

    // ws layout: counts[N] | offsets[N+1] | cursor[N] | blockSums[NB1] |
    //            blockBase[NB1] | perm[M] | pooled[N*FDIM]
    size_t need = ((size_t)(3 * N + 1) + 2 * (size_t)NB1 + (size_t)M) * sizeof(int)
                + (size_t)N * FDIM * sizeof(float);

    if (ws_size >= need && NB1 <= 1024) {
        int*   counts    = (int*)d_ws;
        int*   offsets   = counts + N;
        int*   cursor    = offsets + (N + 1);
        int*   blockSums = cursor + N;
        int*   blockBase = blockSums + NB1;
        int*   perm      = blockBase + NB1;
        float* pooled    = (float*)(perm + M);

        (void)hipMemsetAsync(counts, 0, (size_t)N * sizeof(int), stream);

        dmpnn_hist<<<dim3((M + BLK - 1) / BLK), dim3(BLK), 0, stream>>>(recv, counts, M);
        dmpnn_scan1<<<dim3(NB1), dim3(BLK), 0, stream>>>(counts, blockSums, N);
        dmpnn_scan2<<<dim3(1), dim3(1024), 0, stream>>>(blockSums, blockBase, NB1);
        dmpnn_scan3<<<dim3(NB1), dim3(BLK), 0, stream>>>(counts, blockBase, offsets, cursor, N);
        dmpnn_fill<<<dim3((M + BLK - 1) / BLK), dim3(BLK), 0, stream>>>(recv, cursor, perm, M);

        {
            int wavesPerBlock = 4;                       // 256 threads
            int grid = (N + wavesPerBlock - 1) / wavesPerBlock;
            dmpnn_aggregate<<<dim3(grid), dim3(BLK), 0, stream>>>(
                (const float4*)edges, perm, offsets, (float4*)pooled, N);
        }

        long long total = (long long)M * (FDIM / 4);
        dmpnn_gather_sub<<<dim3((unsigned)((total + BLK - 1) / BLK)), dim3(BLK), 0, stream>>>(
            (const float4*)pooled, (const float4*)edges, send, edge_pairs,
            (float4*)d_out, total);
    } else {
        float* pooled = (float*)d_ws;
        (void)hipMemsetAsync(pooled, 0, (size_t)N * FDIM * sizeof(float), stream);
        long long totalS = (long long)M * FDIM;
        dmpnn_scatter_add<<<dim3((unsigned)((totalS + BLK - 1) / BLK)), dim3(BLK), 0, stream>>>(
            edges, recv, pooled, totalS);
        long long total = (long long)M * (FDIM / 4);
        dmpnn_gather_sub<<<dim3((unsigned)((total + BLK - 1) / BLK)), dim3(BLK), 0, stream>>>(
            (const float4*)pooled, (const float4*)edges, send, edge_pairs,
            (float4*)d_out, total);
    }
}

// Round 6
// 298.087 us; speedup vs baseline: 1.6588x; 1.0028x over previous
//
#include <hip/hip_runtime.h>

#define FDIM 64
#define BLK 256

typedef float f32x4 __attribute__((ext_vector_type(4)));

// ---------------- Atomic fallback ----------------
__global__ void dmpnn_scatter_add(const float* __restrict__ edges,
                                  const int* __restrict__ recv,
                                  float* __restrict__ pooled,
                                  long long total) {
    long long tid = (long long)blockIdx.x * blockDim.x + threadIdx.x;
    if (tid >= total) return;
    int e = (int)(tid >> 6);
    int f = (int)(tid & 63);
    float v = edges[tid];
    int node = recv[e];
    atomicAdd(&pooled[(long long)node * FDIM + f], v);
}

// ---------------- Counting-sort pipeline ----------------
__global__ void dmpnn_hist(const int* __restrict__ recv, int* __restrict__ counts, int M) {
    int e = blockIdx.x * blockDim.x + threadIdx.x;
    if (e >= M) return;
    atomicAdd(&counts[recv[e]], 1);
}

__global__ void dmpnn_scan1(const int* __restrict__ counts, int* __restrict__ blockSums, int N) {
    __shared__ int s[BLK];
    int t = blockIdx.x * BLK + threadIdx.x;
    s[threadIdx.x] = (t < N) ? counts[t] : 0;
    __syncthreads();
    for (int d = BLK >> 1; d > 0; d >>= 1) {
        if (threadIdx.x < (unsigned)d) s[threadIdx.x] += s[threadIdx.x + d];
        __syncthreads();
    }
    if (threadIdx.x == 0) blockSums[blockIdx.x] = s[0];
}

__global__ void dmpnn_scan2(const int* __restrict__ blockSums, int* __restrict__ blockBase, int nb) {
    __shared__ int s[1024];
    int t = threadIdx.x;
    s[t] = (t < nb) ? blockSums[t] : 0;
    __syncthreads();
    for (int d = 1; d < 1024; d <<= 1) {
        int v = (t >= d) ? s[t - d] : 0;
        __syncthreads();
        s[t] += v;
        __syncthreads();
    }
    if (t < nb) blockBase[t] = (t == 0) ? 0 : s[t - 1];
}

__global__ void dmpnn_scan3(const int* __restrict__ counts, const int* __restrict__ blockBase,
                            int* __restrict__ offsets, int* __restrict__ cursor, int N) {
    __shared__ int s[BLK];
    int t = blockIdx.x * BLK + threadIdx.x;
    int c = (t < N) ? counts[t] : 0;
    s[threadIdx.x] = c;
    __syncthreads();
    for (int d = 1; d < BLK; d <<= 1) {
        int v = (threadIdx.x >= (unsigned)d) ? s[threadIdx.x - d] : 0;
        __syncthreads();
        s[threadIdx.x] += v;
        __syncthreads();
    }
    int incl = s[threadIdx.x];
    int excl = incl - c;
    int base = blockBase[blockIdx.x];
    if (t < N) {
        offsets[t] = base + excl;
        cursor[t]  = base + excl;
        if (t == N - 1) offsets[N] = base + incl;
    }
}

__global__ void dmpnn_fill(const int* __restrict__ recv,
                           int* __restrict__ cursor,
                           int* __restrict__ perm, int M) {
    int e = blockIdx.x * blockDim.x + threadIdx.x;
    if (e >= M) return;
    int pos = atomicAdd(&cursor[recv[e]], 1);
    perm[pos] = e;
}

// One wave per node. lane = (slot s = lane>>4, quad q = lane&15).
// 4-deep group-load bundles: 16 edge rows (4 KB) in flight per wave.
__global__ void dmpnn_aggregate(const float* __restrict__ edges,
                                const int* __restrict__ perm,
                                const int* __restrict__ offsets,
                                float4* __restrict__ pooled4, int N) {
    const f32x4* edges4 = (const f32x4*)edges;
    int wave = (int)(((long long)blockIdx.x * blockDim.x + threadIdx.x) >> 6);
    int lane = threadIdx.x & 63;
    if (wave >= N) return;
    int q = lane & 15;
    int s = lane >> 4;
    int lo = offsets[wave];
    int hi = offsets[wave + 1];
    f32x4 acc = {0.f, 0.f, 0.f, 0.f};
    for (int base = lo; base < hi; base += 64) {
        int cnt = hi - base; if (cnt > 64) cnt = 64;
        int cm1 = cnt - 1;
        // one coalesced vector load covers this chunk's perm entries
        int e = perm[base + ((lane < cnt) ? lane : cm1)];
        int ng = (cnt + 3) >> 2;
        int g = 0;
        while (ng - g >= 4) {   // wave-uniform branch
            int i0 = ((g + 0) << 2) + s;
            int i1 = ((g + 1) << 2) + s;
            int i2 = ((g + 2) << 2) + s;
            int i3 = ((g + 3) << 2) + s;
            int e0 = __shfl(e, (i0 < cnt) ? i0 : cm1, 64);
            int e1 = __shfl(e, (i1 < cnt) ? i1 : cm1, 64);
            int e2 = __shfl(e, (i2 < cnt) ? i2 : cm1, 64);
            int e3 = __shfl(e, (i3 < cnt) ? i3 : cm1, 64);
            f32x4 v0 = __builtin_nontemporal_load(&edges4[e0 * 16 + q]);
            f32x4 v1 = __builtin_nontemporal_load(&edges4[e1 * 16 + q]);
            f32x4 v2 = __builtin_nontemporal_load(&edges4[e2 * 16 + q]);
            f32x4 v3 = __builtin_nontemporal_load(&edges4[e3 * 16 + q]);
            if (i0 < cnt) acc += v0;
            if (i1 < cnt) acc += v1;
            if (i2 < cnt) acc += v2;
            if (i3 < cnt) acc += v3;
            g += 4;
        }
        while (g < ng) {        // remainder, wave-uniform
            int i0 = (g << 2) + s;
            int e0 = __shfl(e, (i0 < cnt) ? i0 : cm1, 64);
            f32x4 v0 = __builtin_nontemporal_load(&edges4[e0 * 16 + q]);
            if (i0 < cnt) acc += v0;
            ++g;
        }
    }
    // reduce across the 4 slots (lanes differing in bits 4,5)
    acc.x += __shfl_xor(acc.x, 16, 64);
    acc.y += __shfl_xor(acc.y, 16, 64);
    acc.z += __shfl_xor(acc.z, 16, 64);
    acc.w += __shfl_xor(acc.w, 16, 64);
    acc.x += __shfl_xor(acc.x, 32, 64);
    acc.y += __shfl_xor(acc.y, 32, 64);
    acc.z += __shfl_xor(acc.z, 32, 64);
    acc.w += __shfl_xor(acc.w, 32, 64);
    if (s == 0) {
        float4 r; r.x = acc.x; r.y = acc.y; r.z = acc.z; r.w = acc.w;
        pooled4[wave * 16 + q] = r;
    }
}

// ---------------- Pass 2: gather + subtract, NT output stores ----------------
__global__ void dmpnn_gather_sub(const float4* __restrict__ pooled4,
                                 const float4* __restrict__ edges4,
                                 const int* __restrict__ send,
                                 const int* __restrict__ pair,
                                 float4* __restrict__ out4,
                                 long long total) {
    long long tid = (long long)blockIdx.x * blockDim.x + threadIdx.x;
    if (tid >= total) return;
    int e = (int)(tid >> 4);
    int q = (int)(tid & 15);
    int sn = send[e];
    int pe = pair[e];
    float4 a = pooled4[(long long)sn * 16 + q];
    float4 b = edges4[(long long)pe * 16 + q];
    f32x4 r;
    r.x = a.x - b.x;
    r.y = a.y - b.y;
    r.z = a.z - b.z;
    r.w = a.w - b.w;
    __builtin_nontemporal_store(r, (f32x4*)&out4[tid]);
}

extern "C" void kernel_launch(void* const* d_in, const int* in_sizes, int n_in,
                              void* d_out, int out_size, void* d_ws, size_t ws_size,
                              hipStream_t stream) {
    const float* edges      = (const float*)d_in[1];
    const int*   edge_index = (const int*)d_in[2];   // [2, M] flat
    const int*   edge_pairs = (const int*)d_in[3];   // [1, M] flat

    const int N = in_sizes[0] / FDIM;   // 50000
    const int M = in_sizes[1] / FDIM;   // 1000000

    const int* recv = edge_index;
    const int* send = edge_index + M;

    const int NB1 = (N + BLK - 1) / BLK;

    // ws layout: counts[N] | offsets[N+1] | cursor[N] | blockSums[NB1] |
    //            blockBase[NB1] | perm[M] | pooled[N*FDIM]
    size_t need = ((size_t)(3 * N + 1) + 2 * (size_t)NB1 + (size_t)M) * sizeof(int)
                + (size_t)N * FDIM * sizeof(float);

    if (ws_size >= need && NB1 <= 1024) {
        int*   counts    = (int*)d_ws;
        int*   offsets   = counts + N;
        int*   cursor    = offsets + (N + 1);
        int*   blockSums = cursor + N;
        int*   blockBase = blockSums + NB1;
        int*   perm      = blockBase + NB1;
        float* pooled    = (float*)(perm + M);

        (void)hipMemsetAsync(counts, 0, (size_t)N * sizeof(int), stream);

        dmpnn_hist<<<dim3((M + BLK - 1) / BLK), dim3(BLK), 0, stream>>>(recv, counts, M);
        dmpnn_scan1<<<dim3(NB1), dim3(BLK), 0, stream>>>(counts, blockSums, N);
        dmpnn_scan2<<<dim3(1), dim3(1024), 0, stream>>>(blockSums, blockBase, NB1);
        dmpnn_scan3<<<dim3(NB1), dim3(BLK), 0, stream>>>(counts, blockBase, offsets, cursor, N);
        dmpnn_fill<<<dim3((M + BLK - 1) / BLK), dim3(BLK), 0, stream>>>(recv, cursor, perm, M);

        {
            int wavesPerBlock = 4;                       // 256 threads
            int grid = (N + wavesPerBlock - 1) / wavesPerBlock;
            dmpnn_aggregate<<<dim3(grid), dim3(BLK), 0, stream>>>(
                edges, perm, offsets, (float4*)pooled, N);
        }

        long long total = (long long)M * (FDIM / 4);
        dmpnn_gather_sub<<<dim3((unsigned)((total + BLK - 1) / BLK)), dim3(BLK), 0, stream>>>(
            (const float4*)pooled, (const float4*)edges, send, edge_pairs,
            (float4*)d_out, total);
    } else {
        float* pooled = (float*)d_ws;
        (void)hipMemsetAsync(pooled, 0, (size_t)N * FDIM * sizeof(float), stream);
        long long totalS = (long long)M * FDIM;
        dmpnn_scatter_add<<<dim3((unsigned)((totalS + BLK - 1) / BLK)), dim3(BLK), 0, stream>>>(
            edges, recv, pooled, totalS);
        long long total = (long long)M * (FDIM / 4);
        dmpnn_gather_sub<<<dim3((unsigned)((total + BLK - 1) / BLK)), dim3(BLK), 0, stream>>>(
            (const float4*)pooled, (const float4*)edges, send, edge_pairs,
            (float4*)d_out, total);
    }
}